// Round 1
// baseline (515.100 us; speedup 1.0000x reference)
//
#include <hip/hip_runtime.h>
#include <cstdint>
#include <cstddef>

#define BB   64
#define CINN 64
#define TS   4096
#define FF   128
#define KS   64
#define TOUT (TS - KS + 1)   // 4033
#define TT2  1024

// ---------------- Kernel 1: spatial GEMM + input-square row ----------------
// y[b,fi,t] = sum_c sw[f0+fi,c] * x[b,c,t];  sq[b,t] = sum_c x[b,c,t]^2
__global__ __launch_bounds__(256) void k_spatial(
    const float* __restrict__ x, const float* __restrict__ sw,
    float* __restrict__ y, float* __restrict__ sq, int f0, int fg)
{
    const int tid = threadIdx.x;
    const int b = blockIdx.y;
    const int t = blockIdx.x * 256 + tid;
    const float* xb = x + (size_t)b * CINN * TS + t;
    float xv[CINN];
#pragma unroll
    for (int c = 0; c < CINN; ++c) xv[c] = xb[(size_t)c * TS];
    float s = 0.f;
#pragma unroll
    for (int c = 0; c < CINN; ++c) s += xv[c] * xv[c];
    sq[(size_t)b * TS + t] = s;
    for (int fi = 0; fi < fg; ++fi) {
        const float* swf = sw + (size_t)(f0 + fi) * CINN;  // wave-uniform -> s_load
        float a = 0.f;
#pragma unroll
        for (int c = 0; c < CINN; ++c) a += swf[c] * xv[c];
        y[((size_t)b * fg + fi) * TS + t] = a;
    }
}

// ------------- Kernel 2: temporal conv + cos-sim + reduction ---------------
__global__ __launch_bounds__(256) void k_temporal(
    const float* __restrict__ y, const float* __restrict__ sq,
    const float* __restrict__ cw, const float* __restrict__ sw,
    const float* __restrict__ weight, const float* __restrict__ bias,
    float* __restrict__ out, int f0, int fg)
{
    __shared__ float sqs[TT2 + KS];   // 1088 floats
    __shared__ float wn[FF];
    __shared__ float wred[4];
    const int tid = threadIdx.x;
    const int b = blockIdx.y;
    const int t0 = blockIdx.x * TT2;

    for (int i = tid; i < TT2 + KS; i += 256) {
        int tt = t0 + i; if (tt > TS - 1) tt = TS - 1;
        sqs[i] = sq[(size_t)b * TS + tt];
    }
    if (tid < fg) {
        int f = f0 + tid;
        float ssw = 0.f, scw = 0.f;
        for (int c = 0; c < CINN; ++c) { float v = sw[(size_t)f * CINN + c]; ssw += v * v; }
        for (int k = 0; k < KS; ++k)   { float v = cw[(size_t)f * KS + k];  scw += v * v; }
        wn[tid] = weight[f] * rsqrtf(ssw * scw);   // weight[f]/norm_w[f]
    }
    __syncthreads();

    const int tl = 4 * tid;
    float rinv[4];
    {
        float s = 0.f;
        for (int k = 0; k < KS; ++k) s += sqs[tl + k];
        for (int j = 0; j < 4; ++j) {
            int t = t0 + tl + j;
            rinv[j] = (t < TOUT) ? 64.0f * rsqrtf(s) : 0.0f;  // scale=sqrt(CIN*K)=64
            s += sqs[tl + j + KS] - sqs[tl + j];
        }
    }

    float acc = 0.f;
    for (int fi = 0; fi < fg; ++fi) {
        const float* yrow = y + ((size_t)b * fg + fi) * TS + t0 + tl;
        const float* cwf = cw + (size_t)(f0 + fi) * KS;    // wave-uniform -> s_load
        float4 cur = *(const float4*)yrow;
        float o0 = 0.f, o1 = 0.f, o2 = 0.f, o3 = 0.f;
#pragma unroll
        for (int k4 = 0; k4 < 16; ++k4) {
            float4 nxt = *(const float4*)(yrow + 4 * k4 + 4);  // past-row reads land in sq region (in-bounds, finite, masked)
            float c0 = cwf[4 * k4 + 0], c1 = cwf[4 * k4 + 1];
            float c2 = cwf[4 * k4 + 2], c3 = cwf[4 * k4 + 3];
            o0 += c0 * cur.x + c1 * cur.y + c2 * cur.z + c3 * cur.w;
            o1 += c0 * cur.y + c1 * cur.z + c2 * cur.w + c3 * nxt.x;
            o2 += c0 * cur.z + c1 * cur.w + c2 * nxt.x + c3 * nxt.y;
            o3 += c0 * cur.w + c1 * nxt.x + c2 * nxt.y + c3 * nxt.z;
            cur = nxt;
        }
        acc += wn[fi] * (fabsf(o0) * rinv[0] + fabsf(o1) * rinv[1]
                       + fabsf(o2) * rinv[2] + fabsf(o3) * rinv[3]);
    }

    for (int off = 32; off > 0; off >>= 1) acc += __shfl_down(acc, off, 64);
    if ((tid & 63) == 0) wred[tid >> 6] = acc;
    __syncthreads();
    if (tid == 0) {
        float tot = (wred[0] + wred[1] + wred[2] + wred[3]) * (1.0f / (float)TOUT);
        if (f0 == 0 && blockIdx.x == 0) {
            float bsum = 0.f;
            for (int f = 0; f < FF; ++f) bsum += bias[f];
            tot += bsum;
        }
        atomicAdd(out + b, tot);
    }
}

// --------- Fallback (no workspace): one block per (f,b), LDS rows ----------
__global__ __launch_bounds__(256) void k_naive(
    const float* __restrict__ x, const float* __restrict__ cw,
    const float* __restrict__ sw, const float* __restrict__ weight,
    const float* __restrict__ bias, float* __restrict__ out)
{
    __shared__ float yl[TS];
    __shared__ float ql[TS];
    __shared__ float wred[4];
    const int f = blockIdx.x, b = blockIdx.y, tid = threadIdx.x;
    for (int t = tid; t < TS; t += 256) {
        float a = 0.f, s = 0.f;
        for (int c = 0; c < CINN; ++c) {
            float v = x[((size_t)b * CINN + c) * TS + t];
            a += sw[(size_t)f * CINN + c] * v;
            s += v * v;
        }
        yl[t] = a; ql[t] = s;
    }
    __syncthreads();
    float acc = 0.f;
    for (int t = tid; t < TOUT; t += 256) {
        float cv = 0.f, sl = 0.f;
        for (int k = 0; k < KS; ++k) { cv += cw[(size_t)f * KS + k] * yl[t + k]; sl += ql[t + k]; }
        acc += fabsf(cv) * rsqrtf(sl);
    }
    float ssw = 0.f, scw = 0.f;
    for (int c = 0; c < CINN; ++c) { float v = sw[(size_t)f * CINN + c]; ssw += v * v; }
    for (int k = 0; k < KS; ++k)   { float v = cw[(size_t)f * KS + k];  scw += v * v; }
    const float wnf = weight[f] * rsqrtf(ssw * scw) * 64.0f / (float)TOUT;
    for (int off = 32; off > 0; off >>= 1) acc += __shfl_down(acc, off, 64);
    if ((tid & 63) == 0) wred[tid >> 6] = acc;
    __syncthreads();
    if (tid == 0) {
        float tot = (wred[0] + wred[1] + wred[2] + wred[3]) * wnf;
        if (f == 0) {
            float bsum = 0.f;
            for (int ff = 0; ff < FF; ++ff) bsum += bias[ff];
            tot += bsum;
        }
        atomicAdd(out + b, tot);
    }
}

extern "C" void kernel_launch(void* const* d_in, const int* in_sizes, int n_in,
                              void* d_out, int out_size, void* d_ws, size_t ws_size,
                              hipStream_t stream) {
    const float* x  = (const float*)d_in[0];
    const float* cw = (const float*)d_in[1];   // [F,K]
    const float* sw = (const float*)d_in[2];   // [F,CIN]
    const float* w  = (const float*)d_in[3];   // [F]
    const float* bs = (const float*)d_in[4];   // [F]
    float* out = (float*)d_out;

    hipMemsetAsync(d_out, 0, (size_t)out_size * sizeof(float), stream);

    const size_t sqBytes = (size_t)BB * TS * 4;
    int fg = FF;
    while (fg > 1 && (size_t)BB * fg * TS * 4 + sqBytes > ws_size) fg >>= 1;

    if ((size_t)BB * fg * TS * 4 + sqBytes <= ws_size) {
        float* y  = (float*)d_ws;
        float* sq = (float*)((char*)d_ws + (size_t)BB * fg * TS * 4);
        for (int f0 = 0; f0 < FF; f0 += fg) {
            k_spatial<<<dim3(TS / 256, BB), 256, 0, stream>>>(x, sw, y, sq, f0, fg);
            k_temporal<<<dim3(TS / TT2, BB), 256, 0, stream>>>(y, sq, cw, sw, w, bs, out, f0, fg);
        }
    } else {
        k_naive<<<dim3(FF, BB), 256, 0, stream>>>(x, cw, sw, w, bs, out);
    }
}

// Round 2
// 443.985 us; speedup vs baseline: 1.1602x; 1.1602x over previous
//
#include <hip/hip_runtime.h>
#include <cstdint>
#include <cstddef>

#define BB   64
#define CINN 64
#define TS   4096
#define FF   128
#define KS   64
#define TOUT (TS - KS + 1)   // 4033
#define TT2  1024
#define FGZ  16              // filters per k_temporal block (z-split: 8 chunks)
#define FGS  32              // filters per k_spatial block  (z-split: 4 chunks)

// ---------------- Kernel 1: spatial GEMM + input-square row ----------------
// y[(b*FF+f)*TS + t] = sum_c sw[f,c]*x[b,c,t];  sq[b,t] = sum_c x[b,c,t]^2
__global__ __launch_bounds__(256) void k_spatial(
    const float* __restrict__ x, const float* __restrict__ sw,
    float* __restrict__ y, float* __restrict__ sq)
{
    const int tid = threadIdx.x;
    const int b = blockIdx.y;
    const int f0 = blockIdx.z * FGS;
    const int t = blockIdx.x * 256 + tid;
    const float* xb = x + (size_t)b * CINN * TS + t;
    float xv[CINN];
#pragma unroll
    for (int c = 0; c < CINN; ++c) xv[c] = xb[(size_t)c * TS];
    if (blockIdx.z == 0) {
        float s = 0.f;
#pragma unroll
        for (int c = 0; c < CINN; ++c) s += xv[c] * xv[c];
        sq[(size_t)b * TS + t] = s;
    }
    // 2-way f unroll: two independent fmac chains, s_loads overlapped
    for (int fi = 0; fi < FGS; fi += 2) {
        const float* swf0 = sw + (size_t)(f0 + fi) * CINN;      // wave-uniform -> s_load
        const float* swf1 = swf0 + CINN;
        float a0 = 0.f, a1 = 0.f;
#pragma unroll
        for (int c = 0; c < CINN; ++c) {
            a0 += swf0[c] * xv[c];
            a1 += swf1[c] * xv[c];
        }
        y[((size_t)b * FF + f0 + fi)     * TS + t] = a0;
        y[((size_t)b * FF + f0 + fi + 1) * TS + t] = a1;
    }
}

// ------------- Kernel 2: temporal conv + cos-sim + reduction ---------------
__global__ __launch_bounds__(256) void k_temporal(
    const float* __restrict__ y, const float* __restrict__ sq,
    const float* __restrict__ cw, const float* __restrict__ sw,
    const float* __restrict__ weight, const float* __restrict__ bias,
    float* __restrict__ out)
{
    __shared__ float sqs[TT2 + KS];
    __shared__ float wn[FGZ];
    __shared__ float wred[4];
    const int tid = threadIdx.x;
    const int b = blockIdx.y;
    const int t0 = blockIdx.x * TT2;
    const int f0 = blockIdx.z * FGZ;

    for (int i = tid; i < TT2 + KS; i += 256) {
        int tt = t0 + i; if (tt > TS - 1) tt = TS - 1;
        sqs[i] = sq[(size_t)b * TS + tt];
    }
    if (tid < FGZ) {
        int f = f0 + tid;
        float ssw = 0.f, scw = 0.f;
        for (int c = 0; c < CINN; ++c) { float v = sw[(size_t)f * CINN + c]; ssw += v * v; }
        for (int k = 0; k < KS; ++k)   { float v = cw[(size_t)f * KS + k];  scw += v * v; }
        wn[tid] = weight[f] * rsqrtf(ssw * scw);   // weight[f]/norm_w[f]
    }
    __syncthreads();

    const int tl = 4 * tid;
    float rinv[4];
    {
        float s = 0.f;
        for (int k = 0; k < KS; ++k) s += sqs[tl + k];
        for (int j = 0; j < 4; ++j) {
            int t = t0 + tl + j;
            rinv[j] = (t < TOUT) ? 64.0f * rsqrtf(s) : 0.0f;  // scale=sqrt(CIN*K)=64
            s += sqs[tl + j + KS] - sqs[tl + j];
        }
    }

    float acc = 0.f;
    for (int fi = 0; fi < FGZ; ++fi) {
        const float* yrow = y + ((size_t)b * FF + f0 + fi) * TS + t0 + tl;
        const float* cwf = cw + (size_t)(f0 + fi) * KS;    // wave-uniform -> s_load
        float4 cur = *(const float4*)yrow;
        float o0 = 0.f, o1 = 0.f, o2 = 0.f, o3 = 0.f;
#pragma unroll
        for (int k4 = 0; k4 < 16; ++k4) {
            // tail lanes (t>=TOUT) read past the row into the next f-row / sq
            // region: finite garbage, masked by rinv=0.
            float4 nxt = *(const float4*)(yrow + 4 * k4 + 4);
            float c0 = cwf[4 * k4 + 0], c1 = cwf[4 * k4 + 1];
            float c2 = cwf[4 * k4 + 2], c3 = cwf[4 * k4 + 3];
            o0 += c0 * cur.x + c1 * cur.y + c2 * cur.z + c3 * cur.w;
            o1 += c0 * cur.y + c1 * cur.z + c2 * cur.w + c3 * nxt.x;
            o2 += c0 * cur.z + c1 * cur.w + c2 * nxt.x + c3 * nxt.y;
            o3 += c0 * cur.w + c1 * nxt.x + c2 * nxt.y + c3 * nxt.z;
            cur = nxt;
        }
        acc += wn[fi] * (fabsf(o0) * rinv[0] + fabsf(o1) * rinv[1]
                       + fabsf(o2) * rinv[2] + fabsf(o3) * rinv[3]);
    }

    for (int off = 32; off > 0; off >>= 1) acc += __shfl_down(acc, off, 64);
    if ((tid & 63) == 0) wred[tid >> 6] = acc;
    __syncthreads();
    if (tid == 0) {
        float tot = (wred[0] + wred[1] + wred[2] + wred[3]) * (1.0f / (float)TOUT);
        if (f0 == 0 && blockIdx.x == 0) {
            float bsum = 0.f;
            for (int f = 0; f < FF; ++f) bsum += bias[f];
            tot += bsum;
        }
        atomicAdd(out + b, tot);
    }
}

// --------- Fallback (no workspace): one block per (f,b), LDS rows ----------
__global__ __launch_bounds__(256) void k_naive(
    const float* __restrict__ x, const float* __restrict__ cw,
    const float* __restrict__ sw, const float* __restrict__ weight,
    const float* __restrict__ bias, float* __restrict__ out)
{
    __shared__ float yl[TS];
    __shared__ float ql[TS];
    __shared__ float wred[4];
    const int f = blockIdx.x, b = blockIdx.y, tid = threadIdx.x;
    for (int t = tid; t < TS; t += 256) {
        float a = 0.f, s = 0.f;
        for (int c = 0; c < CINN; ++c) {
            float v = x[((size_t)b * CINN + c) * TS + t];
            a += sw[(size_t)f * CINN + c] * v;
            s += v * v;
        }
        yl[t] = a; ql[t] = s;
    }
    __syncthreads();
    float acc = 0.f;
    for (int t = tid; t < TOUT; t += 256) {
        float cv = 0.f, sl = 0.f;
        for (int k = 0; k < KS; ++k) { cv += cw[(size_t)f * KS + k] * yl[t + k]; sl += ql[t + k]; }
        acc += fabsf(cv) * rsqrtf(sl);
    }
    float ssw = 0.f, scw = 0.f;
    for (int c = 0; c < CINN; ++c) { float v = sw[(size_t)f * CINN + c]; ssw += v * v; }
    for (int k = 0; k < KS; ++k)   { float v = cw[(size_t)f * KS + k];  scw += v * v; }
    const float wnf = weight[f] * rsqrtf(ssw * scw) * 64.0f / (float)TOUT;
    for (int off = 32; off > 0; off >>= 1) acc += __shfl_down(acc, off, 64);
    if ((tid & 63) == 0) wred[tid >> 6] = acc;
    __syncthreads();
    if (tid == 0) {
        float tot = (wred[0] + wred[1] + wred[2] + wred[3]) * wnf;
        if (f == 0) {
            float bsum = 0.f;
            for (int ff = 0; ff < FF; ++ff) bsum += bias[ff];
            tot += bsum;
        }
        atomicAdd(out + b, tot);
    }
}

extern "C" void kernel_launch(void* const* d_in, const int* in_sizes, int n_in,
                              void* d_out, int out_size, void* d_ws, size_t ws_size,
                              hipStream_t stream) {
    const float* x  = (const float*)d_in[0];
    const float* cw = (const float*)d_in[1];   // [F,K]
    const float* sw = (const float*)d_in[2];   // [F,CIN]
    const float* w  = (const float*)d_in[3];   // [F]
    const float* bs = (const float*)d_in[4];   // [F]
    float* out = (float*)d_out;

    hipMemsetAsync(d_out, 0, (size_t)out_size * sizeof(float), stream);

    const size_t yBytes  = (size_t)BB * FF * TS * 4;   // 134 MB
    const size_t sqBytes = (size_t)BB * TS * 4;        // 1 MB

    if (yBytes + sqBytes <= ws_size) {
        float* y  = (float*)d_ws;
        float* sq = (float*)((char*)d_ws + yBytes);
        k_spatial <<<dim3(TS / 256, BB, FF / FGS), 256, 0, stream>>>(x, sw, y, sq);
        k_temporal<<<dim3(TS / TT2, BB, FF / FGZ), 256, 0, stream>>>(y, sq, cw, sw, w, bs, out);
    } else {
        k_naive<<<dim3(FF, BB), 256, 0, stream>>>(x, cw, sw, w, bs, out);
    }
}

// Round 3
// 266.522 us; speedup vs baseline: 1.9327x; 1.6658x over previous
//
#include <hip/hip_runtime.h>
#include <hip/hip_bf16.h>
#include <cstdint>
#include <cstddef>

#define BB   64
#define CINN 64
#define TS   4096
#define FF   128
#define KS   64
#define TOUT (TS - KS + 1)   // 4033
#define TT   2048            // outputs per k_temporal block
#define FGZ  8               // filters per k_temporal block
#define SEG  (TT + KS)       // 2112 staged y values per filter row
#define YLDS (SEG + (SEG / 32) * 4)   // swizzled size: 2376 floats

// swizzled LDS index: insert 4 pad dwords every 32 -> stride-8-float b128
// sliding reads are bank-conflict-free (every 8 consecutive lanes cover all
// 32 banks). float4 at 4-aligned p never crosses a pad boundary.
__device__ __forceinline__ int swz(int p) { return p + ((p >> 5) << 2); }

// ---------------- Kernel 1: spatial GEMM (fp32 in, bf16 y out) + sq ----------------
// y[(b*FF+f)*TS + t] = bf16( sum_c sw[f,c]*x[b,c,t] );  sq[b,t] = sum_c x^2
__global__ __launch_bounds__(256) void k_spatial(
    const float* __restrict__ x, const float* __restrict__ sw,
    __hip_bfloat16* __restrict__ y, float* __restrict__ sq)
{
    const int tid = threadIdx.x;
    const int b = blockIdx.y;
    const int t = blockIdx.x * 256 + tid;
    const float* xb = x + (size_t)b * CINN * TS + t;
    float xv[CINN];
#pragma unroll
    for (int c = 0; c < CINN; ++c) xv[c] = xb[(size_t)c * TS];
    {
        float s = 0.f;
#pragma unroll
        for (int c = 0; c < CINN; ++c) s += xv[c] * xv[c];
        sq[(size_t)b * TS + t] = s;
    }
    // 4-way filter unroll: 4 independent fma chains, scalar weight loads overlap
    for (int f = 0; f < FF; f += 4) {
        const float* w0 = sw + (size_t)f * CINN;
        const float* w1 = w0 + CINN;
        const float* w2 = w0 + 2 * CINN;
        const float* w3 = w0 + 3 * CINN;
        float a0 = 0.f, a1 = 0.f, a2 = 0.f, a3 = 0.f;
#pragma unroll
        for (int c = 0; c < CINN; ++c) {
            float v = xv[c];
            a0 += w0[c] * v; a1 += w1[c] * v; a2 += w2[c] * v; a3 += w3[c] * v;
        }
        __hip_bfloat16* yb = y + ((size_t)b * FF + f) * TS + t;
        yb[0]          = __float2bfloat16(a0);
        yb[TS]         = __float2bfloat16(a1);
        yb[2 * (size_t)TS] = __float2bfloat16(a2);
        yb[3 * (size_t)TS] = __float2bfloat16(a3);
    }
}

// ------------- Kernel 2: temporal conv from LDS-staged bf16 y -------------
__global__ __launch_bounds__(256) void k_temporal(
    const __hip_bfloat16* __restrict__ y, const float* __restrict__ sq,
    const float* __restrict__ cw, const float* __restrict__ sw,
    const float* __restrict__ weight, const float* __restrict__ bias,
    float* __restrict__ out)
{
    __shared__ float ybuf[YLDS];
    __shared__ float sqs[SEG];
    __shared__ float wn[FGZ];
    __shared__ float wred[4];
    const int tid = threadIdx.x;
    const int b = blockIdx.y;
    const int t0 = blockIdx.x * TT;
    const int f0 = blockIdx.z * FGZ;

    // ---- stage sq segment (fp32 float4, coalesced) ----
    const float* sqrow = sq + (size_t)b * TS;
#pragma unroll
    for (int it = 0; it < 3; ++it) {
        int j = tid + 256 * it;            // float4 index, SEG/4 = 528
        if (j < SEG / 4) {
            int p = t0 + 4 * j; if (p > TS - 4) p = TS - 4;   // clamp (masked tail)
            float4 v = *(const float4*)(sqrow + p);
            *(float4*)(sqs + 4 * j) = v;
        }
    }
    // ---- per-filter weight norm ----
    if (tid < FGZ) {
        int f = f0 + tid;
        float ssw = 0.f, scw = 0.f;
        for (int c = 0; c < CINN; ++c) { float v = sw[(size_t)f * CINN + c]; ssw += v * v; }
        for (int k = 0; k < KS; ++k)   { float v = cw[(size_t)f * KS + k];  scw += v * v; }
        wn[tid] = weight[f] * rsqrtf(ssw * scw) * (64.0f / (float)TOUT); // scale & 1/TOUT folded
    }
    // ---- prefetch y stage for filter 0 (uint2 = 4 bf16, coalesced) ----
    uint2 u0, u1, u2;
    {
        const uint2* r = (const uint2*)(y + ((size_t)b * FF + f0) * TS);
        int g;
        g = tid;       { int gg = t0 / 4 + g; if (gg > TS / 4 - 1) gg = TS / 4 - 1; u0 = r[gg]; }
        g = tid + 256; { int gg = t0 / 4 + g; if (gg > TS / 4 - 1) gg = TS / 4 - 1; u1 = r[gg]; }
        g = tid + 512; if (g < SEG / 4) { int gg = t0 / 4 + g; if (gg > TS / 4 - 1) gg = TS / 4 - 1; u2 = r[gg]; }
    }
    __syncthreads();

    // ---- sliding input-norm rinv for this thread's 8 outputs ----
    const int base = 8 * tid;
    float rv[8];
    {
        float hd[8], tl[8];
        float s = 0.f;
#pragma unroll
        for (int m = 0; m < 16; ++m) {
            float4 v = *(const float4*)(sqs + base + 4 * m);
            if (m < 2) { hd[4 * m] = v.x; hd[4 * m + 1] = v.y; hd[4 * m + 2] = v.z; hd[4 * m + 3] = v.w; }
            s += (v.x + v.y) + (v.z + v.w);
        }
        float4 ta = *(const float4*)(sqs + base + 64);
        float4 tb = *(const float4*)(sqs + base + 68);
        tl[0] = ta.x; tl[1] = ta.y; tl[2] = ta.z; tl[3] = ta.w;
        tl[4] = tb.x; tl[5] = tb.y; tl[6] = tb.z; tl[7] = tb.w;
#pragma unroll
        for (int j = 0; j < 8; ++j) {
            int t = t0 + base + j;
            rv[j] = (t < TOUT) ? rsqrtf(s) : 0.f;
            s += tl[j] - hd[j];
        }
    }

    // ---- filter loop: write staged regs -> LDS, prefetch next, compute ----
    float acc = 0.f;
    for (int fi = 0; fi < FGZ; ++fi) {
        // unpack bf16 pairs -> swizzled fp32 LDS (float4 per group of 4)
        {
            int g;
            float4 v;
            g = tid;
            v.x = __uint_as_float(u0.x << 16); v.y = __uint_as_float(u0.x & 0xffff0000u);
            v.z = __uint_as_float(u0.y << 16); v.w = __uint_as_float(u0.y & 0xffff0000u);
            *(float4*)(ybuf + swz(4 * g)) = v;
            g = tid + 256;
            v.x = __uint_as_float(u1.x << 16); v.y = __uint_as_float(u1.x & 0xffff0000u);
            v.z = __uint_as_float(u1.y << 16); v.w = __uint_as_float(u1.y & 0xffff0000u);
            *(float4*)(ybuf + swz(4 * g)) = v;
            g = tid + 512;
            if (g < SEG / 4) {
                v.x = __uint_as_float(u2.x << 16); v.y = __uint_as_float(u2.x & 0xffff0000u);
                v.z = __uint_as_float(u2.y << 16); v.w = __uint_as_float(u2.y & 0xffff0000u);
                *(float4*)(ybuf + swz(4 * g)) = v;
            }
        }
        __syncthreads();
        // prefetch next filter's segment (latency hidden behind compute below)
        if (fi + 1 < FGZ) {
            const uint2* r = (const uint2*)(y + ((size_t)b * FF + f0 + fi + 1) * TS);
            int g;
            g = tid;       { int gg = t0 / 4 + g; if (gg > TS / 4 - 1) gg = TS / 4 - 1; u0 = r[gg]; }
            g = tid + 256; { int gg = t0 / 4 + g; if (gg > TS / 4 - 1) gg = TS / 4 - 1; u1 = r[gg]; }
            g = tid + 512; if (g < SEG / 4) { int gg = t0 / 4 + g; if (gg > TS / 4 - 1) gg = TS / 4 - 1; u2 = r[gg]; }
        }
        // sliding 64-tap conv, 8 outputs/thread, from swizzled LDS
        const float* cwf = cw + (size_t)(f0 + fi) * KS;   // wave-uniform -> s_load
        float4 A  = *(const float4*)(ybuf + swz(base));
        float4 Bv = *(const float4*)(ybuf + swz(base + 4));
        float4 Cv = *(const float4*)(ybuf + swz(base + 8));
        float o0 = 0.f, o1 = 0.f, o2 = 0.f, o3 = 0.f;
        float o4 = 0.f, o5 = 0.f, o6 = 0.f, o7 = 0.f;
#pragma unroll
        for (int k4 = 0; k4 < 16; ++k4) {
            float c0 = cwf[4 * k4 + 0], c1 = cwf[4 * k4 + 1];
            float c2 = cwf[4 * k4 + 2], c3 = cwf[4 * k4 + 3];
            o0 += c0 * A.x  + c1 * A.y  + c2 * A.z  + c3 * A.w;
            o1 += c0 * A.y  + c1 * A.z  + c2 * A.w  + c3 * Bv.x;
            o2 += c0 * A.z  + c1 * A.w  + c2 * Bv.x + c3 * Bv.y;
            o3 += c0 * A.w  + c1 * Bv.x + c2 * Bv.y + c3 * Bv.z;
            o4 += c0 * Bv.x + c1 * Bv.y + c2 * Bv.z + c3 * Bv.w;
            o5 += c0 * Bv.y + c1 * Bv.z + c2 * Bv.w + c3 * Cv.x;
            o6 += c0 * Bv.z + c1 * Bv.w + c2 * Cv.x + c3 * Cv.y;
            o7 += c0 * Bv.w + c1 * Cv.x + c2 * Cv.y + c3 * Cv.z;
            A = Bv; Bv = Cv;
            if (k4 < 15) Cv = *(const float4*)(ybuf + swz(base + 12 + 4 * k4));
        }
        float ssum = fabsf(o0) * rv[0];
        ssum += fabsf(o1) * rv[1]; ssum += fabsf(o2) * rv[2];
        ssum += fabsf(o3) * rv[3]; ssum += fabsf(o4) * rv[4];
        ssum += fabsf(o5) * rv[5]; ssum += fabsf(o6) * rv[6];
        ssum += fabsf(o7) * rv[7];
        acc += wn[fi] * ssum;
        __syncthreads();   // all reads of ybuf done before next iter's writes
    }

    // ---- block reduction + atomic ----
    for (int off = 32; off > 0; off >>= 1) acc += __shfl_down(acc, off, 64);
    if ((tid & 63) == 0) wred[tid >> 6] = acc;
    __syncthreads();
    if (tid == 0) atomicAdd(out + b, wred[0] + wred[1] + wred[2] + wred[3]);
    // bias: add once per b (designated block), wave-reduced
    if (blockIdx.x == 0 && blockIdx.z == 0 && tid < FF) {
        float v = bias[tid];
        for (int off = 32; off > 0; off >>= 1) v += __shfl_down(v, off, 64);
        if ((tid & 63) == 0) atomicAdd(out + b, v);
    }
}

// --------- Fallback (no workspace): one block per (f,b), LDS rows ----------
__global__ __launch_bounds__(256) void k_naive(
    const float* __restrict__ x, const float* __restrict__ cw,
    const float* __restrict__ sw, const float* __restrict__ weight,
    const float* __restrict__ bias, float* __restrict__ out)
{
    __shared__ float yl[TS];
    __shared__ float ql[TS];
    __shared__ float wred[4];
    const int f = blockIdx.x, b = blockIdx.y, tid = threadIdx.x;
    for (int t = tid; t < TS; t += 256) {
        float a = 0.f, s = 0.f;
        for (int c = 0; c < CINN; ++c) {
            float v = x[((size_t)b * CINN + c) * TS + t];
            a += sw[(size_t)f * CINN + c] * v;
            s += v * v;
        }
        yl[t] = a; ql[t] = s;
    }
    __syncthreads();
    float acc = 0.f;
    for (int t = tid; t < TOUT; t += 256) {
        float cv = 0.f, sl = 0.f;
        for (int k = 0; k < KS; ++k) { cv += cw[(size_t)f * KS + k] * yl[t + k]; sl += ql[t + k]; }
        acc += fabsf(cv) * rsqrtf(sl);
    }
    float ssw = 0.f, scw = 0.f;
    for (int c = 0; c < CINN; ++c) { float v = sw[(size_t)f * CINN + c]; ssw += v * v; }
    for (int k = 0; k < KS; ++k)   { float v = cw[(size_t)f * KS + k];  scw += v * v; }
    const float wnf = weight[f] * rsqrtf(ssw * scw) * 64.0f / (float)TOUT;
    for (int off = 32; off > 0; off >>= 1) acc += __shfl_down(acc, off, 64);
    if ((tid & 63) == 0) wred[tid >> 6] = acc;
    __syncthreads();
    if (tid == 0) {
        float tot = (wred[0] + wred[1] + wred[2] + wred[3]) * wnf;
        if (f == 0) {
            float bsum = 0.f;
            for (int ff = 0; ff < FF; ++ff) bsum += bias[ff];
            tot += bsum;
        }
        atomicAdd(out + b, tot);
    }
}

extern "C" void kernel_launch(void* const* d_in, const int* in_sizes, int n_in,
                              void* d_out, int out_size, void* d_ws, size_t ws_size,
                              hipStream_t stream) {
    const float* x  = (const float*)d_in[0];
    const float* cw = (const float*)d_in[1];   // [F,K]
    const float* sw = (const float*)d_in[2];   // [F,CIN]
    const float* w  = (const float*)d_in[3];   // [F]
    const float* bs = (const float*)d_in[4];   // [F]
    float* out = (float*)d_out;

    hipMemsetAsync(d_out, 0, (size_t)out_size * sizeof(float), stream);

    const size_t yBytes  = (size_t)BB * FF * TS * sizeof(__hip_bfloat16); // 67 MB
    const size_t sqBytes = (size_t)BB * TS * sizeof(float);               // 1 MB

    if (yBytes + sqBytes <= ws_size) {
        __hip_bfloat16* ybf = (__hip_bfloat16*)d_ws;
        float* sq = (float*)((char*)d_ws + yBytes);
        k_spatial <<<dim3(TS / 256, BB), 256, 0, stream>>>(x, sw, ybf, sq);
        k_temporal<<<dim3(TS / TT, BB, FF / FGZ), 256, 0, stream>>>(ybf, sq, cw, sw, w, bs, out);
    } else {
        k_naive<<<dim3(FF, BB), 256, 0, stream>>>(x, cw, sw, w, bs, out);
    }
}

// Round 4
// 256.361 us; speedup vs baseline: 2.0093x; 1.0396x over previous
//
#include <hip/hip_runtime.h>
#include <hip/hip_bf16.h>
#include <cstdint>
#include <cstddef>

#define BB   64
#define CINN 64
#define TS   4096
#define FF   128
#define KS   64
#define TOUT (TS - KS + 1)   // 4033
#define TT   2048            // outputs per k_temporal block
#define FGZ  8               // filters per k_temporal block
#define SEG  (TT + KS)       // 2112 staged y values per filter row
#define YLDS (SEG + (SEG / 32) * 4)   // swizzled size: 2376 floats

// swizzled LDS index: insert 4 pad dwords every 32 -> stride-8-float b128
// sliding reads are bank-conflict-free. float4 at 4-aligned p never crosses
// a pad boundary.
__device__ __forceinline__ int swz(int p) { return p + ((p >> 5) << 2); }

// ---------------- Kernel 1: spatial GEMM (fp32 in, bf16 y out) + sq ----------------
// launch_bounds(256,2): allow ~100+ VGPRs so xv[64] stays in registers.
// (R3 post-mortem: default budget was 60 VGPR -> xv spilled to scratch,
//  100 us instead of ~30.)
__global__ __launch_bounds__(256, 2) void k_spatial(
    const float* __restrict__ x, const float* __restrict__ sw,
    __hip_bfloat16* __restrict__ y, float* __restrict__ sq)
{
    const int tid = threadIdx.x;
    const int b = blockIdx.y;
    const int t = blockIdx.x * 256 + tid;
    const float* xb = x + (size_t)b * CINN * TS + t;
    float xv[CINN];
#pragma unroll
    for (int c = 0; c < CINN; ++c) xv[c] = xb[(size_t)c * TS];
    {
        float s = 0.f;
#pragma unroll
        for (int c = 0; c < CINN; ++c) s += xv[c] * xv[c];
        sq[(size_t)b * TS + t] = s;
    }
    // 4-way filter unroll: 4 independent fma chains, scalar weight loads overlap
    for (int f = 0; f < FF; f += 4) {
        const float* w0 = sw + (size_t)f * CINN;
        const float* w1 = w0 + CINN;
        const float* w2 = w0 + 2 * CINN;
        const float* w3 = w0 + 3 * CINN;
        float a0 = 0.f, a1 = 0.f, a2 = 0.f, a3 = 0.f;
#pragma unroll
        for (int c = 0; c < CINN; ++c) {
            float v = xv[c];
            a0 += w0[c] * v; a1 += w1[c] * v; a2 += w2[c] * v; a3 += w3[c] * v;
        }
        __hip_bfloat16* yb = y + ((size_t)b * FF + f) * TS + t;
        yb[0]              = __float2bfloat16(a0);
        yb[TS]             = __float2bfloat16(a1);
        yb[2 * (size_t)TS] = __float2bfloat16(a2);
        yb[3 * (size_t)TS] = __float2bfloat16(a3);
    }
}

// ------------- Kernel 2: temporal conv from LDS-staged bf16 y -------------
// Double-buffered y stage (buf1 doubles as the sq staging buffer, which is
// dead after the prologue) -> one barrier per filter, prefetch issued before
// the compute block and drained at the phase-end barrier after it.
__global__ __launch_bounds__(256) void k_temporal(
    const __hip_bfloat16* __restrict__ y, const float* __restrict__ sq,
    const float* __restrict__ cw, const float* __restrict__ sw,
    const float* __restrict__ weight, const float* __restrict__ bias,
    float* __restrict__ out)
{
    __shared__ float buf0[YLDS];
    __shared__ float buf1[YLDS];   // prologue: sq staging; then odd-filter y buffer
    __shared__ float wn[FGZ];
    __shared__ float wred[4];
    const int tid = threadIdx.x;
    const int b = blockIdx.y;
    const int t0 = blockIdx.x * TT;
    const int f0 = blockIdx.z * FGZ;

    // ---- stage sq segment into buf1 (linear layout) ----
    const float* sqrow = sq + (size_t)b * TS;
#pragma unroll
    for (int it = 0; it < 3; ++it) {
        int j = tid + 256 * it;            // float4 index, SEG/4 = 528
        if (j < SEG / 4) {
            int p = t0 + 4 * j; if (p > TS - 4) p = TS - 4;   // clamp (masked tail)
            float4 v = *(const float4*)(sqrow + p);
            *(float4*)(buf1 + 4 * j) = v;
        }
    }
    // ---- prefetch y stage for filter f0 (uint2 = 4 bf16, coalesced) ----
    uint2 u0, u1, u2;
    {
        const uint2* r = (const uint2*)(y + ((size_t)b * FF + f0) * TS);
        int gg;
        gg = t0 / 4 + tid;       if (gg > TS / 4 - 1) gg = TS / 4 - 1; u0 = r[gg];
        gg = t0 / 4 + tid + 256; if (gg > TS / 4 - 1) gg = TS / 4 - 1; u1 = r[gg];
        if (tid + 512 < SEG / 4) {
            gg = t0 / 4 + tid + 512; if (gg > TS / 4 - 1) gg = TS / 4 - 1; u2 = r[gg];
        }
    }
    // ---- per-filter weight norm ----
    if (tid < FGZ) {
        int f = f0 + tid;
        float ssw = 0.f, scw = 0.f;
        for (int c = 0; c < CINN; ++c) { float v = sw[(size_t)f * CINN + c]; ssw += v * v; }
        for (int k = 0; k < KS; ++k)   { float v = cw[(size_t)f * KS + k];  scw += v * v; }
        wn[tid] = weight[f] * rsqrtf(ssw * scw) * (64.0f / (float)TOUT); // scale & 1/TOUT folded
    }
    __syncthreads();

    // ---- sliding input-norm rinv for this thread's 8 outputs (reads buf1) ----
    const int base = 8 * tid;
    float rv[8];
    {
        float hd[8], tl[8];
        float s = 0.f;
#pragma unroll
        for (int m = 0; m < 16; ++m) {
            float4 v = *(const float4*)(buf1 + base + 4 * m);
            if (m < 2) { hd[4 * m] = v.x; hd[4 * m + 1] = v.y; hd[4 * m + 2] = v.z; hd[4 * m + 3] = v.w; }
            s += (v.x + v.y) + (v.z + v.w);
        }
        float4 ta = *(const float4*)(buf1 + base + 64);
        float4 tb = *(const float4*)(buf1 + base + 68);
        tl[0] = ta.x; tl[1] = ta.y; tl[2] = ta.z; tl[3] = ta.w;
        tl[4] = tb.x; tl[5] = tb.y; tl[6] = tb.z; tl[7] = tb.w;
#pragma unroll
        for (int j = 0; j < 8; ++j) {
            int tpos = t0 + base + j;
            rv[j] = (tpos < TOUT) ? rsqrtf(s) : 0.f;
            s += tl[j] - hd[j];
        }
    }

    // ---- unpack filter f0 into buf0; prefetch f1 ----
    {
        float4 v;
        v.x = __uint_as_float(u0.x << 16); v.y = __uint_as_float(u0.x & 0xffff0000u);
        v.z = __uint_as_float(u0.y << 16); v.w = __uint_as_float(u0.y & 0xffff0000u);
        *(float4*)(buf0 + swz(4 * tid)) = v;
        v.x = __uint_as_float(u1.x << 16); v.y = __uint_as_float(u1.x & 0xffff0000u);
        v.z = __uint_as_float(u1.y << 16); v.w = __uint_as_float(u1.y & 0xffff0000u);
        *(float4*)(buf0 + swz(4 * (tid + 256))) = v;
        if (tid + 512 < SEG / 4) {
            v.x = __uint_as_float(u2.x << 16); v.y = __uint_as_float(u2.x & 0xffff0000u);
            v.z = __uint_as_float(u2.y << 16); v.w = __uint_as_float(u2.y & 0xffff0000u);
            *(float4*)(buf0 + swz(4 * (tid + 512))) = v;
        }
    }
    if (1 < FGZ) {
        const uint2* r = (const uint2*)(y + ((size_t)b * FF + f0 + 1) * TS);
        int gg;
        gg = t0 / 4 + tid;       if (gg > TS / 4 - 1) gg = TS / 4 - 1; u0 = r[gg];
        gg = t0 / 4 + tid + 256; if (gg > TS / 4 - 1) gg = TS / 4 - 1; u1 = r[gg];
        if (tid + 512 < SEG / 4) {
            gg = t0 / 4 + tid + 512; if (gg > TS / 4 - 1) gg = TS / 4 - 1; u2 = r[gg];
        }
    }
    __syncthreads();

    // ---- filter loop: one barrier per filter, prefetch overlaps compute ----
    float acc = 0.f;
    for (int fi = 0; fi < FGZ; ++fi) {
        float* curb = (fi & 1) ? buf1 : buf0;
        float* nxtb = (fi & 1) ? buf0 : buf1;
        // write NEXT filter's segment into the other buffer (u holds fi+1)
        if (fi + 1 < FGZ) {
            float4 v;
            v.x = __uint_as_float(u0.x << 16); v.y = __uint_as_float(u0.x & 0xffff0000u);
            v.z = __uint_as_float(u0.y << 16); v.w = __uint_as_float(u0.y & 0xffff0000u);
            *(float4*)(nxtb + swz(4 * tid)) = v;
            v.x = __uint_as_float(u1.x << 16); v.y = __uint_as_float(u1.x & 0xffff0000u);
            v.z = __uint_as_float(u1.y << 16); v.w = __uint_as_float(u1.y & 0xffff0000u);
            *(float4*)(nxtb + swz(4 * (tid + 256))) = v;
            if (tid + 512 < SEG / 4) {
                v.x = __uint_as_float(u2.x << 16); v.y = __uint_as_float(u2.x & 0xffff0000u);
                v.z = __uint_as_float(u2.y << 16); v.w = __uint_as_float(u2.y & 0xffff0000u);
                *(float4*)(nxtb + swz(4 * (tid + 512))) = v;
            }
            // prefetch fi+2 (drained at this phase's end barrier, after compute)
            if (fi + 2 < FGZ) {
                const uint2* r = (const uint2*)(y + ((size_t)b * FF + f0 + fi + 2) * TS);
                int gg;
                gg = t0 / 4 + tid;       if (gg > TS / 4 - 1) gg = TS / 4 - 1; u0 = r[gg];
                gg = t0 / 4 + tid + 256; if (gg > TS / 4 - 1) gg = TS / 4 - 1; u1 = r[gg];
                if (tid + 512 < SEG / 4) {
                    gg = t0 / 4 + tid + 512; if (gg > TS / 4 - 1) gg = TS / 4 - 1; u2 = r[gg];
                }
            }
        }
        // sliding 64-tap conv, 8 outputs/thread, from swizzled LDS (curb)
        const float* cwf = cw + (size_t)(f0 + fi) * KS;   // wave-uniform -> s_load
        float4 A  = *(const float4*)(curb + swz(base));
        float4 Bv = *(const float4*)(curb + swz(base + 4));
        float4 Cv = *(const float4*)(curb + swz(base + 8));
        float o0 = 0.f, o1 = 0.f, o2 = 0.f, o3 = 0.f;
        float o4 = 0.f, o5 = 0.f, o6 = 0.f, o7 = 0.f;
#pragma unroll
        for (int k4 = 0; k4 < 16; ++k4) {
            float c0 = cwf[4 * k4 + 0], c1 = cwf[4 * k4 + 1];
            float c2 = cwf[4 * k4 + 2], c3 = cwf[4 * k4 + 3];
            o0 += c0 * A.x  + c1 * A.y  + c2 * A.z  + c3 * A.w;
            o1 += c0 * A.y  + c1 * A.z  + c2 * A.w  + c3 * Bv.x;
            o2 += c0 * A.z  + c1 * A.w  + c2 * Bv.x + c3 * Bv.y;
            o3 += c0 * A.w  + c1 * Bv.x + c2 * Bv.y + c3 * Bv.z;
            o4 += c0 * Bv.x + c1 * Bv.y + c2 * Bv.z + c3 * Bv.w;
            o5 += c0 * Bv.y + c1 * Bv.z + c2 * Bv.w + c3 * Cv.x;
            o6 += c0 * Bv.z + c1 * Bv.w + c2 * Cv.x + c3 * Cv.y;
            o7 += c0 * Bv.w + c1 * Cv.x + c2 * Cv.y + c3 * Cv.z;
            A = Bv; Bv = Cv;
            if (k4 < 15) Cv = *(const float4*)(curb + swz(base + 12 + 4 * k4));
        }
        float ssum = fabsf(o0) * rv[0];
        ssum += fabsf(o1) * rv[1]; ssum += fabsf(o2) * rv[2];
        ssum += fabsf(o3) * rv[3]; ssum += fabsf(o4) * rv[4];
        ssum += fabsf(o5) * rv[5]; ssum += fabsf(o6) * rv[6];
        ssum += fabsf(o7) * rv[7];
        acc += wn[fi] * ssum;
        __syncthreads();   // separates curb reads from next phase's curb writes
    }

    // ---- block reduction + atomic ----
    for (int off = 32; off > 0; off >>= 1) acc += __shfl_down(acc, off, 64);
    if ((tid & 63) == 0) wred[tid >> 6] = acc;
    __syncthreads();
    if (tid == 0) atomicAdd(out + b, wred[0] + wred[1] + wred[2] + wred[3]);
    // bias: add once per b (designated block), wave-reduced
    if (blockIdx.x == 0 && blockIdx.z == 0 && tid < FF) {
        float v = bias[tid];
        for (int off = 32; off > 0; off >>= 1) v += __shfl_down(v, off, 64);
        if ((tid & 63) == 0) atomicAdd(out + b, v);
    }
}

// --------- Fallback (no workspace): one block per (f,b), LDS rows ----------
__global__ __launch_bounds__(256) void k_naive(
    const float* __restrict__ x, const float* __restrict__ cw,
    const float* __restrict__ sw, const float* __restrict__ weight,
    const float* __restrict__ bias, float* __restrict__ out)
{
    __shared__ float yl[TS];
    __shared__ float ql[TS];
    __shared__ float wred[4];
    const int f = blockIdx.x, b = blockIdx.y, tid = threadIdx.x;
    for (int t = tid; t < TS; t += 256) {
        float a = 0.f, s = 0.f;
        for (int c = 0; c < CINN; ++c) {
            float v = x[((size_t)b * CINN + c) * TS + t];
            a += sw[(size_t)f * CINN + c] * v;
            s += v * v;
        }
        yl[t] = a; ql[t] = s;
    }
    __syncthreads();
    float acc = 0.f;
    for (int t = tid; t < TOUT; t += 256) {
        float cv = 0.f, sl = 0.f;
        for (int k = 0; k < KS; ++k) { cv += cw[(size_t)f * KS + k] * yl[t + k]; sl += ql[t + k]; }
        acc += fabsf(cv) * rsqrtf(sl);
    }
    float ssw = 0.f, scw = 0.f;
    for (int c = 0; c < CINN; ++c) { float v = sw[(size_t)f * CINN + c]; ssw += v * v; }
    for (int k = 0; k < KS; ++k)   { float v = cw[(size_t)f * KS + k];  scw += v * v; }
    const float wnf = weight[f] * rsqrtf(ssw * scw) * 64.0f / (float)TOUT;
    for (int off = 32; off > 0; off >>= 1) acc += __shfl_down(acc, off, 64);
    if ((tid & 63) == 0) wred[tid >> 6] = acc;
    __syncthreads();
    if (tid == 0) {
        float tot = (wred[0] + wred[1] + wred[2] + wred[3]) * wnf;
        if (f == 0) {
            float bsum = 0.f;
            for (int ff = 0; ff < FF; ++ff) bsum += bias[ff];
            tot += bsum;
        }
        atomicAdd(out + b, tot);
    }
}

extern "C" void kernel_launch(void* const* d_in, const int* in_sizes, int n_in,
                              void* d_out, int out_size, void* d_ws, size_t ws_size,
                              hipStream_t stream) {
    const float* x  = (const float*)d_in[0];
    const float* cw = (const float*)d_in[1];   // [F,K]
    const float* sw = (const float*)d_in[2];   // [F,CIN]
    const float* w  = (const float*)d_in[3];   // [F]
    const float* bs = (const float*)d_in[4];   // [F]
    float* out = (float*)d_out;

    hipMemsetAsync(d_out, 0, (size_t)out_size * sizeof(float), stream);

    const size_t yBytes  = (size_t)BB * FF * TS * sizeof(__hip_bfloat16); // 67 MB
    const size_t sqBytes = (size_t)BB * TS * sizeof(float);               // 1 MB

    if (yBytes + sqBytes <= ws_size) {
        __hip_bfloat16* ybf = (__hip_bfloat16*)d_ws;
        float* sq = (float*)((char*)d_ws + yBytes);
        k_spatial <<<dim3(TS / 256, BB), 256, 0, stream>>>(x, sw, ybf, sq);
        k_temporal<<<dim3(TS / TT, BB, FF / FGZ), 256, 0, stream>>>(ybf, sq, cw, sw, w, bs, out);
    } else {
        k_naive<<<dim3(FF, BB), 256, 0, stream>>>(x, cw, sw, w, bs, out);
    }
}

// Round 5
// 192.283 us; speedup vs baseline: 2.6789x; 1.3332x over previous
//
#include <hip/hip_runtime.h>
#include <hip/hip_bf16.h>
#include <cstdint>
#include <cstddef>

#define BB   64
#define CINN 64
#define TS   4096
#define FF   128
#define KS   64
#define TOUT (TS - KS + 1)   // 4033
#define TT   2048            // outputs per k_temporal block
#define FGZ  8               // filters per k_temporal block
#define SEG  (TT + KS)       // 2112 staged y values per filter row
#define YLDS (SEG + (SEG / 32) * 4)   // swizzled size: 2376 floats

// k_spatial_mfma tiling
#define TPB   256            // t per block
#define SXT   37             // xT row stride in dwords (74 bf16, odd -> conflict-free frag reads)
#define SYB   68             // ybuf row stride in dwords (16B-aligned b128 readback)

typedef __attribute__((ext_vector_type(8))) short short8;
typedef __attribute__((ext_vector_type(4))) float f32x4;
union FragU { unsigned int u[4]; short8 v; };

static __device__ __forceinline__ unsigned int f2bf_u(float f) {
    __hip_bfloat16 h = __float2bfloat16(f);
    return (unsigned int)*reinterpret_cast<unsigned short*>(&h);
}

// swizzled LDS index for k_temporal (unchanged from R3)
__device__ __forceinline__ int swz(int p) { return p + ((p >> 5) << 2); }

// ============ Kernel 1: spatial GEMM via MFMA (bf16), + sq ============
// y[(b*FF+f)*TS + t] = bf16( sum_c sw[f,c]*x[b,c,t] );  sq[b,t] = sum_c x^2
__global__ __launch_bounds__(256) void k_spatial_mfma(
    const float* __restrict__ x, const float* __restrict__ sw,
    __hip_bfloat16* __restrict__ y, float* __restrict__ sq)
{
    __shared__ unsigned int xTd[TPB * SXT];   // xT[t][c] bf16-pairs: 37888 B
    __shared__ float ybuf[4 * 32 * SYB];      // per-wave epilogue staging: 34816 B
    __shared__ float sqred[4 * TPB];          // 4096 B
    const int tid = threadIdx.x;
    const int b = blockIdx.y;
    const int t0 = blockIdx.x * TPB;

    // ---- stage x -> xT (bf16 c-pairs), accumulate sq partials ----
    {
        const int tj = tid & 63;      // t-quad index (4 t each)
        const int cg = tid >> 6;      // c-pair group (16 channels per group)
        float4 s4 = {0.f, 0.f, 0.f, 0.f};
#pragma unroll
        for (int i = 0; i < 8; ++i) {
            int cp = cg * 8 + i;      // c-pair index 0..31
            const float* xr = x + ((size_t)b * CINN + 2 * cp) * TS + t0 + 4 * tj;
            float4 v0 = *(const float4*)xr;
            float4 v1 = *(const float4*)(xr + TS);
            s4.x += v0.x * v0.x + v1.x * v1.x;
            s4.y += v0.y * v0.y + v1.y * v1.y;
            s4.z += v0.z * v0.z + v1.z * v1.z;
            s4.w += v0.w * v0.w + v1.w * v1.w;
            xTd[(4 * tj + 0) * SXT + cp] = f2bf_u(v0.x) | (f2bf_u(v1.x) << 16);
            xTd[(4 * tj + 1) * SXT + cp] = f2bf_u(v0.y) | (f2bf_u(v1.y) << 16);
            xTd[(4 * tj + 2) * SXT + cp] = f2bf_u(v0.z) | (f2bf_u(v1.z) << 16);
            xTd[(4 * tj + 3) * SXT + cp] = f2bf_u(v0.w) | (f2bf_u(v1.w) << 16);
        }
        *(float4*)(sqred + cg * TPB + 4 * tj) = s4;
    }
    __syncthreads();
    if (tid < 64) {
        float4 a0 = *(const float4*)(sqred + 4 * tid);
        float4 a1 = *(const float4*)(sqred + TPB + 4 * tid);
        float4 a2 = *(const float4*)(sqred + 2 * TPB + 4 * tid);
        float4 a3 = *(const float4*)(sqred + 3 * TPB + 4 * tid);
        float4 s; s.x = a0.x + a1.x + a2.x + a3.x; s.y = a0.y + a1.y + a2.y + a3.y;
        s.z = a0.z + a1.z + a2.z + a3.z; s.w = a0.w + a1.w + a2.w + a3.w;
        *(float4*)(sq + (size_t)b * TS + t0 + 4 * tid) = s;
    }

    // ---- MFMA: wave w computes f-local [32w, 32w+32) x t-tile [t0, t0+256) ----
    const int w  = tid >> 6;
    const int ln = tid & 63;
    const int m  = ln & 15;     // A-row / B-col / D-col index
    const int q  = ln >> 4;     // k-quad
    const int fbase = 32 * w;

    // A fragments: sw[f][c] bf16, A[p][s]: p = f-tile (16 f), s = K-step (32 c)
    short8 Afr[2][2];
#pragma unroll
    for (int p = 0; p < 2; ++p)
#pragma unroll
        for (int s = 0; s < 2; ++s) {
            const float* swr = sw + (size_t)(fbase + 16 * p + m) * CINN + s * 32 + q * 8;
            float4 w0 = *(const float4*)swr;
            float4 w1 = *(const float4*)(swr + 4);
            FragU fa;
            fa.u[0] = f2bf_u(w0.x) | (f2bf_u(w0.y) << 16);
            fa.u[1] = f2bf_u(w0.z) | (f2bf_u(w0.w) << 16);
            fa.u[2] = f2bf_u(w1.x) | (f2bf_u(w1.y) << 16);
            fa.u[3] = f2bf_u(w1.z) | (f2bf_u(w1.w) << 16);
            Afr[p][s] = fa.v;
        }

    const int baseB = m * SXT + q * 4;
    float* yb = ybuf + w * (32 * SYB);

#pragma unroll
    for (int strip = 0; strip < 4; ++strip) {
#pragma unroll
        for (int tti = 0; tti < 4; ++tti) {
            const int tt = strip * 4 + tti;
            const int ad = baseB + tt * (16 * SXT);
            FragU b0, b1;
#pragma unroll
            for (int i = 0; i < 4; ++i) { b0.u[i] = xTd[ad + i]; b1.u[i] = xTd[ad + 16 + i]; }
            f32x4 acc0 = {0.f, 0.f, 0.f, 0.f};
            f32x4 acc1 = {0.f, 0.f, 0.f, 0.f};
            acc0 = __builtin_amdgcn_mfma_f32_16x16x32_bf16(Afr[0][0], b0.v, acc0, 0, 0, 0);
            acc0 = __builtin_amdgcn_mfma_f32_16x16x32_bf16(Afr[0][1], b1.v, acc0, 0, 0, 0);
            acc1 = __builtin_amdgcn_mfma_f32_16x16x32_bf16(Afr[1][0], b0.v, acc1, 0, 0, 0);
            acc1 = __builtin_amdgcn_mfma_f32_16x16x32_bf16(Afr[1][1], b1.v, acc1, 0, 0, 0);
            // D layout: col(t)=lane&15, row(f)=4*(lane>>4)+reg  [m89-verified]
            const int tl = tti * 16 + m;
#pragma unroll
            for (int r = 0; r < 4; ++r) {
                yb[(4 * q + r) * SYB + tl]        = acc0[r];
                yb[(16 + 4 * q + r) * SYB + tl]   = acc1[r];
            }
        }
        // readback + coalesced bf16 store: lane covers t-quad 4*m of f-row (pr*4+q)
#pragma unroll
        for (int pr = 0; pr < 8; ++pr) {
            const int fl = pr * 4 + q;
            float4 v = *(const float4*)(yb + fl * SYB + 4 * m);
            uint2 o;
            o.x = f2bf_u(v.x) | (f2bf_u(v.y) << 16);
            o.y = f2bf_u(v.z) | (f2bf_u(v.w) << 16);
            *(uint2*)(y + ((size_t)b * FF + fbase + fl) * TS + t0 + strip * 64 + 4 * m) = o;
        }
    }
}

// ------------- Kernel 2: temporal conv from LDS-staged bf16 y (unchanged R3) -------------
__global__ __launch_bounds__(256) void k_temporal(
    const __hip_bfloat16* __restrict__ y, const float* __restrict__ sq,
    const float* __restrict__ cw, const float* __restrict__ sw,
    const float* __restrict__ weight, const float* __restrict__ bias,
    float* __restrict__ out)
{
    __shared__ float buf0[YLDS];
    __shared__ float buf1[YLDS];   // prologue: sq staging; then odd-filter y buffer
    __shared__ float wn[FGZ];
    __shared__ float wred[4];
    const int tid = threadIdx.x;
    const int b = blockIdx.y;
    const int t0 = blockIdx.x * TT;
    const int f0 = blockIdx.z * FGZ;

    const float* sqrow = sq + (size_t)b * TS;
#pragma unroll
    for (int it = 0; it < 3; ++it) {
        int j = tid + 256 * it;
        if (j < SEG / 4) {
            int p = t0 + 4 * j; if (p > TS - 4) p = TS - 4;
            float4 v = *(const float4*)(sqrow + p);
            *(float4*)(buf1 + 4 * j) = v;
        }
    }
    uint2 u0, u1, u2;
    {
        const uint2* r = (const uint2*)(y + ((size_t)b * FF + f0) * TS);
        int gg;
        gg = t0 / 4 + tid;       if (gg > TS / 4 - 1) gg = TS / 4 - 1; u0 = r[gg];
        gg = t0 / 4 + tid + 256; if (gg > TS / 4 - 1) gg = TS / 4 - 1; u1 = r[gg];
        if (tid + 512 < SEG / 4) {
            gg = t0 / 4 + tid + 512; if (gg > TS / 4 - 1) gg = TS / 4 - 1; u2 = r[gg];
        }
    }
    if (tid < FGZ) {
        int f = f0 + tid;
        float ssw = 0.f, scw = 0.f;
        for (int c = 0; c < CINN; ++c) { float v = sw[(size_t)f * CINN + c]; ssw += v * v; }
        for (int k = 0; k < KS; ++k)   { float v = cw[(size_t)f * KS + k];  scw += v * v; }
        wn[tid] = weight[f] * rsqrtf(ssw * scw) * (64.0f / (float)TOUT);
    }
    __syncthreads();

    const int base = 8 * tid;
    float rv[8];
    {
        float hd[8], tl[8];
        float s = 0.f;
#pragma unroll
        for (int mm = 0; mm < 16; ++mm) {
            float4 v = *(const float4*)(buf1 + base + 4 * mm);
            if (mm < 2) { hd[4 * mm] = v.x; hd[4 * mm + 1] = v.y; hd[4 * mm + 2] = v.z; hd[4 * mm + 3] = v.w; }
            s += (v.x + v.y) + (v.z + v.w);
        }
        float4 ta = *(const float4*)(buf1 + base + 64);
        float4 tb = *(const float4*)(buf1 + base + 68);
        tl[0] = ta.x; tl[1] = ta.y; tl[2] = ta.z; tl[3] = ta.w;
        tl[4] = tb.x; tl[5] = tb.y; tl[6] = tb.z; tl[7] = tb.w;
#pragma unroll
        for (int j = 0; j < 8; ++j) {
            int tpos = t0 + base + j;
            rv[j] = (tpos < TOUT) ? rsqrtf(s) : 0.f;
            s += tl[j] - hd[j];
        }
    }

    {
        float4 v;
        v.x = __uint_as_float(u0.x << 16); v.y = __uint_as_float(u0.x & 0xffff0000u);
        v.z = __uint_as_float(u0.y << 16); v.w = __uint_as_float(u0.y & 0xffff0000u);
        *(float4*)(buf0 + swz(4 * tid)) = v;
        v.x = __uint_as_float(u1.x << 16); v.y = __uint_as_float(u1.x & 0xffff0000u);
        v.z = __uint_as_float(u1.y << 16); v.w = __uint_as_float(u1.y & 0xffff0000u);
        *(float4*)(buf0 + swz(4 * (tid + 256))) = v;
        if (tid + 512 < SEG / 4) {
            v.x = __uint_as_float(u2.x << 16); v.y = __uint_as_float(u2.x & 0xffff0000u);
            v.z = __uint_as_float(u2.y << 16); v.w = __uint_as_float(u2.y & 0xffff0000u);
            *(float4*)(buf0 + swz(4 * (tid + 512))) = v;
        }
    }
    {
        const uint2* r = (const uint2*)(y + ((size_t)b * FF + f0 + 1) * TS);
        int gg;
        gg = t0 / 4 + tid;       if (gg > TS / 4 - 1) gg = TS / 4 - 1; u0 = r[gg];
        gg = t0 / 4 + tid + 256; if (gg > TS / 4 - 1) gg = TS / 4 - 1; u1 = r[gg];
        if (tid + 512 < SEG / 4) {
            gg = t0 / 4 + tid + 512; if (gg > TS / 4 - 1) gg = TS / 4 - 1; u2 = r[gg];
        }
    }
    __syncthreads();

    float acc = 0.f;
    for (int fi = 0; fi < FGZ; ++fi) {
        float* curb = (fi & 1) ? buf1 : buf0;
        float* nxtb = (fi & 1) ? buf0 : buf1;
        if (fi + 1 < FGZ) {
            float4 v;
            v.x = __uint_as_float(u0.x << 16); v.y = __uint_as_float(u0.x & 0xffff0000u);
            v.z = __uint_as_float(u0.y << 16); v.w = __uint_as_float(u0.y & 0xffff0000u);
            *(float4*)(nxtb + swz(4 * tid)) = v;
            v.x = __uint_as_float(u1.x << 16); v.y = __uint_as_float(u1.x & 0xffff0000u);
            v.z = __uint_as_float(u1.y << 16); v.w = __uint_as_float(u1.y & 0xffff0000u);
            *(float4*)(nxtb + swz(4 * (tid + 256))) = v;
            if (tid + 512 < SEG / 4) {
                v.x = __uint_as_float(u2.x << 16); v.y = __uint_as_float(u2.x & 0xffff0000u);
                v.z = __uint_as_float(u2.y << 16); v.w = __uint_as_float(u2.y & 0xffff0000u);
                *(float4*)(nxtb + swz(4 * (tid + 512))) = v;
            }
            if (fi + 2 < FGZ) {
                const uint2* r = (const uint2*)(y + ((size_t)b * FF + f0 + fi + 2) * TS);
                int gg;
                gg = t0 / 4 + tid;       if (gg > TS / 4 - 1) gg = TS / 4 - 1; u0 = r[gg];
                gg = t0 / 4 + tid + 256; if (gg > TS / 4 - 1) gg = TS / 4 - 1; u1 = r[gg];
                if (tid + 512 < SEG / 4) {
                    gg = t0 / 4 + tid + 512; if (gg > TS / 4 - 1) gg = TS / 4 - 1; u2 = r[gg];
                }
            }
        }
        const float* cwf = cw + (size_t)(f0 + fi) * KS;
        float4 A  = *(const float4*)(curb + swz(base));
        float4 Bv = *(const float4*)(curb + swz(base + 4));
        float4 Cv = *(const float4*)(curb + swz(base + 8));
        float o0 = 0.f, o1 = 0.f, o2 = 0.f, o3 = 0.f;
        float o4 = 0.f, o5 = 0.f, o6 = 0.f, o7 = 0.f;
#pragma unroll
        for (int k4 = 0; k4 < 16; ++k4) {
            float c0 = cwf[4 * k4 + 0], c1 = cwf[4 * k4 + 1];
            float c2 = cwf[4 * k4 + 2], c3 = cwf[4 * k4 + 3];
            o0 += c0 * A.x  + c1 * A.y  + c2 * A.z  + c3 * A.w;
            o1 += c0 * A.y  + c1 * A.z  + c2 * A.w  + c3 * Bv.x;
            o2 += c0 * A.z  + c1 * A.w  + c2 * Bv.x + c3 * Bv.y;
            o3 += c0 * A.w  + c1 * Bv.x + c2 * Bv.y + c3 * Bv.z;
            o4 += c0 * Bv.x + c1 * Bv.y + c2 * Bv.z + c3 * Bv.w;
            o5 += c0 * Bv.y + c1 * Bv.z + c2 * Bv.w + c3 * Cv.x;
            o6 += c0 * Bv.z + c1 * Bv.w + c2 * Cv.x + c3 * Cv.y;
            o7 += c0 * Bv.w + c1 * Cv.x + c2 * Cv.y + c3 * Cv.z;
            A = Bv; Bv = Cv;
            if (k4 < 15) Cv = *(const float4*)(curb + swz(base + 12 + 4 * k4));
        }
        float ssum = fabsf(o0) * rv[0];
        ssum += fabsf(o1) * rv[1]; ssum += fabsf(o2) * rv[2];
        ssum += fabsf(o3) * rv[3]; ssum += fabsf(o4) * rv[4];
        ssum += fabsf(o5) * rv[5]; ssum += fabsf(o6) * rv[6];
        ssum += fabsf(o7) * rv[7];
        acc += wn[fi] * ssum;
        __syncthreads();
    }

    for (int off = 32; off > 0; off >>= 1) acc += __shfl_down(acc, off, 64);
    if ((tid & 63) == 0) wred[tid >> 6] = acc;
    __syncthreads();
    if (tid == 0) atomicAdd(out + b, wred[0] + wred[1] + wred[2] + wred[3]);
    if (blockIdx.x == 0 && blockIdx.z == 0 && tid < FF) {
        float v = bias[tid];
        for (int off = 32; off > 0; off >>= 1) v += __shfl_down(v, off, 64);
        if ((tid & 63) == 0) atomicAdd(out + b, v);
    }
}

// --------- Fallback (no workspace): one block per (f,b), LDS rows ----------
__global__ __launch_bounds__(256) void k_naive(
    const float* __restrict__ x, const float* __restrict__ cw,
    const float* __restrict__ sw, const float* __restrict__ weight,
    const float* __restrict__ bias, float* __restrict__ out)
{
    __shared__ float yl[TS];
    __shared__ float ql[TS];
    __shared__ float wred[4];
    const int f = blockIdx.x, b = blockIdx.y, tid = threadIdx.x;
    for (int t = tid; t < TS; t += 256) {
        float a = 0.f, s = 0.f;
        for (int c = 0; c < CINN; ++c) {
            float v = x[((size_t)b * CINN + c) * TS + t];
            a += sw[(size_t)f * CINN + c] * v;
            s += v * v;
        }
        yl[t] = a; ql[t] = s;
    }
    __syncthreads();
    float acc = 0.f;
    for (int t = tid; t < TOUT; t += 256) {
        float cv = 0.f, sl = 0.f;
        for (int k = 0; k < KS; ++k) { cv += cw[(size_t)f * KS + k] * yl[t + k]; sl += ql[t + k]; }
        acc += fabsf(cv) * rsqrtf(sl);
    }
    float ssw = 0.f, scw = 0.f;
    for (int c = 0; c < CINN; ++c) { float v = sw[(size_t)f * CINN + c]; ssw += v * v; }
    for (int k = 0; k < KS; ++k)   { float v = cw[(size_t)f * KS + k];  scw += v * v; }
    const float wnf = weight[f] * rsqrtf(ssw * scw) * 64.0f / (float)TOUT;
    for (int off = 32; off > 0; off >>= 1) acc += __shfl_down(acc, off, 64);
    if ((tid & 63) == 0) wred[tid >> 6] = acc;
    __syncthreads();
    if (tid == 0) {
        float tot = (wred[0] + wred[1] + wred[2] + wred[3]) * wnf;
        if (f == 0) {
            float bsum = 0.f;
            for (int ff = 0; ff < FF; ++ff) bsum += bias[ff];
            tot += bsum;
        }
        atomicAdd(out + b, tot);
    }
}

extern "C" void kernel_launch(void* const* d_in, const int* in_sizes, int n_in,
                              void* d_out, int out_size, void* d_ws, size_t ws_size,
                              hipStream_t stream) {
    const float* x  = (const float*)d_in[0];
    const float* cw = (const float*)d_in[1];   // [F,K]
    const float* sw = (const float*)d_in[2];   // [F,CIN]
    const float* w  = (const float*)d_in[3];   // [F]
    const float* bs = (const float*)d_in[4];   // [F]
    float* out = (float*)d_out;

    hipMemsetAsync(d_out, 0, (size_t)out_size * sizeof(float), stream);

    const size_t yBytes  = (size_t)BB * FF * TS * sizeof(__hip_bfloat16); // 67 MB
    const size_t sqBytes = (size_t)BB * TS * sizeof(float);               // 1 MB

    if (yBytes + sqBytes <= ws_size) {
        __hip_bfloat16* ybf = (__hip_bfloat16*)d_ws;
        float* sq = (float*)((char*)d_ws + yBytes);
        k_spatial_mfma<<<dim3(TS / TPB, BB), 256, 0, stream>>>(x, sw, ybf, sq);
        k_temporal<<<dim3(TS / TT, BB, FF / FGZ), 256, 0, stream>>>(ybf, sq, cw, sw, w, bs, out);
    } else {
        k_naive<<<dim3(FF, BB), 256, 0, stream>>>(x, cw, sw, w, bs, out);
    }
}

// Round 6
// 145.656 us; speedup vs baseline: 3.5364x; 1.3201x over previous
//
#include <hip/hip_runtime.h>
#include <hip/hip_bf16.h>
#include <cstdint>
#include <cstddef>

#define BB   64
#define CINN 64
#define TS   4096
#define FF   128
#define KS   64
#define TOUT (TS - KS + 1)   // 4033
#define TT   2048            // outputs per k_temporal block (8 tiles of 256)
#define FGZ  8               // filters per k_temporal block
#define SEG  (TT + KS)       // 2112 sq values staged for rinv
#define SEG2 2432            // staged bf16 y per filter row (need 2048+336, uint2-mult)
#define YDW  (SEG2 / 2)      // 1216 dwords
#define YLDSW (YDW + (YDW / 32) * 4)   // 1368 swizzled dwords

// k_spatial_mfma tiling (unchanged from R4 — validated)
#define TPB   256
#define SXT   37
#define SYB   68

typedef __attribute__((ext_vector_type(8))) short short8;
typedef __attribute__((ext_vector_type(4))) float f32x4;
union FragU { unsigned int u[4]; short8 v; uint4 q4; };

static __device__ __forceinline__ unsigned int f2bf_u(float f) {
    __hip_bfloat16 h = __float2bfloat16(f);
    return (unsigned int)*reinterpret_cast<unsigned short*>(&h);
}

// pad 4 dwords every 32 -> sliding b128 reads are <=2-way (free) conflicts
__device__ __forceinline__ int swz(int p) { return p + ((p >> 5) << 2); }

// ============ Kernel 1: spatial GEMM via MFMA (bf16), + sq  [R4, unchanged] ============
__global__ __launch_bounds__(256) void k_spatial_mfma(
    const float* __restrict__ x, const float* __restrict__ sw,
    __hip_bfloat16* __restrict__ y, float* __restrict__ sq)
{
    __shared__ unsigned int xTd[TPB * SXT];
    __shared__ float ybuf[4 * 32 * SYB];
    __shared__ float sqred[4 * TPB];
    const int tid = threadIdx.x;
    const int b = blockIdx.y;
    const int t0 = blockIdx.x * TPB;

    {
        const int tj = tid & 63;
        const int cg = tid >> 6;
        float4 s4 = {0.f, 0.f, 0.f, 0.f};
#pragma unroll
        for (int i = 0; i < 8; ++i) {
            int cp = cg * 8 + i;
            const float* xr = x + ((size_t)b * CINN + 2 * cp) * TS + t0 + 4 * tj;
            float4 v0 = *(const float4*)xr;
            float4 v1 = *(const float4*)(xr + TS);
            s4.x += v0.x * v0.x + v1.x * v1.x;
            s4.y += v0.y * v0.y + v1.y * v1.y;
            s4.z += v0.z * v0.z + v1.z * v1.z;
            s4.w += v0.w * v0.w + v1.w * v1.w;
            xTd[(4 * tj + 0) * SXT + cp] = f2bf_u(v0.x) | (f2bf_u(v1.x) << 16);
            xTd[(4 * tj + 1) * SXT + cp] = f2bf_u(v0.y) | (f2bf_u(v1.y) << 16);
            xTd[(4 * tj + 2) * SXT + cp] = f2bf_u(v0.z) | (f2bf_u(v1.z) << 16);
            xTd[(4 * tj + 3) * SXT + cp] = f2bf_u(v0.w) | (f2bf_u(v1.w) << 16);
        }
        *(float4*)(sqred + cg * TPB + 4 * tj) = s4;
    }
    __syncthreads();
    if (tid < 64) {
        float4 a0 = *(const float4*)(sqred + 4 * tid);
        float4 a1 = *(const float4*)(sqred + TPB + 4 * tid);
        float4 a2 = *(const float4*)(sqred + 2 * TPB + 4 * tid);
        float4 a3 = *(const float4*)(sqred + 3 * TPB + 4 * tid);
        float4 s; s.x = a0.x + a1.x + a2.x + a3.x; s.y = a0.y + a1.y + a2.y + a3.y;
        s.z = a0.z + a1.z + a2.z + a3.z; s.w = a0.w + a1.w + a2.w + a3.w;
        *(float4*)(sq + (size_t)b * TS + t0 + 4 * tid) = s;
    }

    const int w  = tid >> 6;
    const int ln = tid & 63;
    const int m  = ln & 15;
    const int q  = ln >> 4;
    const int fbase = 32 * w;

    short8 Afr[2][2];
#pragma unroll
    for (int p = 0; p < 2; ++p)
#pragma unroll
        for (int s = 0; s < 2; ++s) {
            const float* swr = sw + (size_t)(fbase + 16 * p + m) * CINN + s * 32 + q * 8;
            float4 w0 = *(const float4*)swr;
            float4 w1 = *(const float4*)(swr + 4);
            FragU fa;
            fa.u[0] = f2bf_u(w0.x) | (f2bf_u(w0.y) << 16);
            fa.u[1] = f2bf_u(w0.z) | (f2bf_u(w0.w) << 16);
            fa.u[2] = f2bf_u(w1.x) | (f2bf_u(w1.y) << 16);
            fa.u[3] = f2bf_u(w1.z) | (f2bf_u(w1.w) << 16);
            Afr[p][s] = fa.v;
        }

    const int baseB = m * SXT + q * 4;
    float* yb = ybuf + w * (32 * SYB);

#pragma unroll
    for (int strip = 0; strip < 4; ++strip) {
#pragma unroll
        for (int tti = 0; tti < 4; ++tti) {
            const int tt = strip * 4 + tti;
            const int ad = baseB + tt * (16 * SXT);
            FragU b0, b1;
#pragma unroll
            for (int i = 0; i < 4; ++i) { b0.u[i] = xTd[ad + i]; b1.u[i] = xTd[ad + 16 + i]; }
            f32x4 acc0 = {0.f, 0.f, 0.f, 0.f};
            f32x4 acc1 = {0.f, 0.f, 0.f, 0.f};
            acc0 = __builtin_amdgcn_mfma_f32_16x16x32_bf16(Afr[0][0], b0.v, acc0, 0, 0, 0);
            acc0 = __builtin_amdgcn_mfma_f32_16x16x32_bf16(Afr[0][1], b1.v, acc0, 0, 0, 0);
            acc1 = __builtin_amdgcn_mfma_f32_16x16x32_bf16(Afr[1][0], b0.v, acc1, 0, 0, 0);
            acc1 = __builtin_amdgcn_mfma_f32_16x16x32_bf16(Afr[1][1], b1.v, acc1, 0, 0, 0);
            const int tl = tti * 16 + m;
#pragma unroll
            for (int r = 0; r < 4; ++r) {
                yb[(4 * q + r) * SYB + tl]      = acc0[r];
                yb[(16 + 4 * q + r) * SYB + tl] = acc1[r];
            }
        }
#pragma unroll
        for (int pr = 0; pr < 8; ++pr) {
            const int fl = pr * 4 + q;
            float4 v = *(const float4*)(yb + fl * SYB + 4 * m);
            uint2 o;
            o.x = f2bf_u(v.x) | (f2bf_u(v.y) << 16);
            o.y = f2bf_u(v.z) | (f2bf_u(v.w) << 16);
            *(uint2*)(y + ((size_t)b * FF + fbase + fl) * TS + t0 + strip * 64 + 4 * m) = o;
        }
    }
}

// ============ Kernel 2: temporal conv via banded MFMA ============
// out[t0+16m+n] = sum_s sum_k A_s[m][k]*B_s[k][n],
//   A_s[m][k] = y[t0+16m+32s+k]  (b128 from swizzled bf16 LDS)
//   B_s[k][n] = cw[32s+k-n] if in [0,64) else 0  (built per filter from padded cw)
__global__ __launch_bounds__(256) void k_temporal_mfma(
    const __hip_bfloat16* __restrict__ y, const float* __restrict__ sq,
    const float* __restrict__ cw, const float* __restrict__ sw,
    const float* __restrict__ weight, const float* __restrict__ bias,
    float* __restrict__ out)
{
    __shared__ unsigned int ydb[2][YLDSW];  // bf16-pair y stage, double-buffered
    __shared__ float rbuf[SEG];             // sq staging -> then rinv in D-layout order
    __shared__ float cwp[2][112];           // zero-padded cw (idx-15 in [0,64)), dbuf
    __shared__ float wn[FGZ];
    __shared__ float wred[4];
    const int tid = threadIdx.x;
    const int ln  = tid & 63;
    const int w   = tid >> 6;
    const int n   = ln & 15;    // A-row m AND B-col n (both = lane&15)
    const int q   = ln >> 4;    // k-octet selector
    const int b   = blockIdx.y;
    const int t0  = blockIdx.x * TT;
    const int f0  = blockIdx.z * FGZ;

    // ---- prologue: stage sq -> rbuf (linear) ----
    const float* sqrow = sq + (size_t)b * TS;
#pragma unroll
    for (int it = 0; it < 3; ++it) {
        int j = tid + 256 * it;            // float4 index, SEG/4 = 528
        if (j < SEG / 4) {
            int p = t0 + 4 * j; if (p > TS - 4) p = TS - 4;
            *(float4*)(rbuf + 4 * j) = *(const float4*)(sqrow + p);
        }
    }
    // cwp for filter f0
    if (tid < 112) {
        float v = 0.f; int ci = tid - 15;
        if (ci >= 0 && ci < KS) v = cw[(size_t)f0 * KS + ci];
        cwp[0][tid] = v;
    }
    // per-filter weight norms (fp32)
    if (tid < FGZ) {
        int f = f0 + tid;
        float ssw = 0.f, scw = 0.f;
        for (int c = 0; c < CINN; ++c) { float v = sw[(size_t)f * CINN + c]; ssw += v * v; }
        for (int k = 0; k < KS; ++k)   { float v = cw[(size_t)f * KS + k];  scw += v * v; }
        wn[tid] = weight[f] * rsqrtf(ssw * scw) * (64.0f / (float)TOUT);
    }
    // prefetch y row f0 (uint2 = 4 bf16, coalesced; SEG2/4 = 608)
    uint2 u0, u1, u2;
    {
        const uint2* r = (const uint2*)(y + ((size_t)b * FF + f0) * TS);
        int gg;
        gg = t0 / 4 + tid;       if (gg > TS / 4 - 1) gg = TS / 4 - 1; u0 = r[gg];
        gg = t0 / 4 + tid + 256; if (gg > TS / 4 - 1) gg = TS / 4 - 1; u1 = r[gg];
        if (tid < SEG2 / 4 - 512) {
            gg = t0 / 4 + tid + 512; if (gg > TS / 4 - 1) gg = TS / 4 - 1; u2 = r[gg];
        }
    }
    __syncthreads();   // A: sq/cwp/wn visible

    // ---- rinv per thread (8 t's) from linear rbuf; write ydb[0] concurrently ----
    const int base = 8 * tid;
    float rv[8];
    {
        float hd[8], tl[8];
        float s = 0.f;
#pragma unroll
        for (int mm = 0; mm < 16; ++mm) {
            float4 v = *(const float4*)(rbuf + base + 4 * mm);
            if (mm < 2) { hd[4 * mm] = v.x; hd[4 * mm + 1] = v.y; hd[4 * mm + 2] = v.z; hd[4 * mm + 3] = v.w; }
            s += (v.x + v.y) + (v.z + v.w);
        }
        float4 ta = *(const float4*)(rbuf + base + 64);
        float4 tb = *(const float4*)(rbuf + base + 68);
        tl[0] = ta.x; tl[1] = ta.y; tl[2] = ta.z; tl[3] = ta.w;
        tl[4] = tb.x; tl[5] = tb.y; tl[6] = tb.z; tl[7] = tb.w;
#pragma unroll
        for (int j = 0; j < 8; ++j) {
            int tpos = t0 + base + j;
            rv[j] = (tpos < TOUT) ? rsqrtf(s) : 0.f;   // masks tail AND clamped-y garbage
            s += tl[j] - hd[j];
        }
    }
    // stage y f0 -> ydb[0] (raw bf16 pairs, swizzled; b64 writes, conflict-free)
    *(uint2*)(ydb[0] + swz(2 * tid))         = u0;
    *(uint2*)(ydb[0] + swz(2 * (tid + 256))) = u1;
    if (tid < SEG2 / 4 - 512) *(uint2*)(ydb[0] + swz(2 * (tid + 512))) = u2;
    // prefetch y row f0+1
    if (1 < FGZ) {
        const uint2* r = (const uint2*)(y + ((size_t)b * FF + f0 + 1) * TS);
        int gg;
        gg = t0 / 4 + tid;       if (gg > TS / 4 - 1) gg = TS / 4 - 1; u0 = r[gg];
        gg = t0 / 4 + tid + 256; if (gg > TS / 4 - 1) gg = TS / 4 - 1; u1 = r[gg];
        if (tid < SEG2 / 4 - 512) {
            gg = t0 / 4 + tid + 512; if (gg > TS / 4 - 1) gg = TS / 4 - 1; u2 = r[gg];
        }
    }
    __syncthreads();   // B: all rv reads of rbuf done
    // scatter rinv into D-layout order: t=tile*256+16m+n -> tile*256 + (q*16+n)*4 + (m&3)
#pragma unroll
    for (int j = 0; j < 8; ++j) {
        int tl = base + j;
        int nn = tl & 15, mr = (tl >> 4) & 15, tile = tl >> 8;
        rbuf[tile * 256 + ((mr >> 2) * 16 + nn) * 4 + (mr & 3)] = rv[j];
    }
    __syncthreads();   // C: rinv + ydb[0] visible

    // ---- filter loop: one barrier per filter ----
    float acc = 0.f;
    for (int fi = 0; fi < FGZ; ++fi) {
        const int buf = fi & 1;
        // write NEXT filter's y into the other buffer; load cwp for fi+1
        if (fi + 1 < FGZ) {
            *(uint2*)(ydb[buf ^ 1] + swz(2 * tid))         = u0;
            *(uint2*)(ydb[buf ^ 1] + swz(2 * (tid + 256))) = u1;
            if (tid < SEG2 / 4 - 512) *(uint2*)(ydb[buf ^ 1] + swz(2 * (tid + 512))) = u2;
            if (tid >= 144 && tid < 144 + 112) {
                int u = tid - 144; float v = 0.f; int ci = u - 15;
                if (ci >= 0 && ci < KS) v = cw[(size_t)(f0 + fi + 1) * KS + ci];
                cwp[buf ^ 1][u] = v;
            }
            // prefetch fi+2 (drained at this iteration's end barrier)
            if (fi + 2 < FGZ) {
                const uint2* r = (const uint2*)(y + ((size_t)b * FF + f0 + fi + 2) * TS);
                int gg;
                gg = t0 / 4 + tid;       if (gg > TS / 4 - 1) gg = TS / 4 - 1; u0 = r[gg];
                gg = t0 / 4 + tid + 256; if (gg > TS / 4 - 1) gg = TS / 4 - 1; u1 = r[gg];
                if (tid < SEG2 / 4 - 512) {
                    gg = t0 / 4 + tid + 512; if (gg > TS / 4 - 1) gg = TS / 4 - 1; u2 = r[gg];
                }
            }
        }
        // build banded-B fragments for this filter (from cwp[buf], 2-way-conflict b32)
        short8 Bf[3];
#pragma unroll
        for (int s = 0; s < 3; ++s) {
            const int off = 15 + 32 * s + 8 * q - n;   // in [0, 104]
            FragU fb;
#pragma unroll
            for (int i = 0; i < 4; ++i)
                fb.u[i] = f2bf_u(cwp[buf][off + 2 * i]) | (f2bf_u(cwp[buf][off + 2 * i + 1]) << 16);
            Bf[s] = fb.v;
        }
        // 2 tiles (256 outputs each) per wave: 3 MFMA + 4 b128 per tile
        float facc = 0.f;
#pragma unroll
        for (int ti = 0; ti < 2; ++ti) {
            const int tile = 2 * w + ti;
            f32x4 d = {0.f, 0.f, 0.f, 0.f};
#pragma unroll
            for (int s = 0; s < 3; ++s) {
                FragU fa;
                fa.q4 = *(const uint4*)(ydb[buf] + swz(tile * 128 + 8 * n + 16 * s + 4 * q));
                d = __builtin_amdgcn_mfma_f32_16x16x32_bf16(fa.v, Bf[s], d, 0, 0, 0);
            }
            float4 r4 = *(const float4*)(rbuf + tile * 256 + 4 * ln);
            float rr[4]; *(float4*)rr = r4;
#pragma unroll
            for (int r = 0; r < 4; ++r) facc += fabsf(d[r]) * rr[r];
        }
        acc += wn[fi] * facc;
        __syncthreads();   // curb reads done before next iteration's writes
    }

    // ---- block reduction + atomic ----
    for (int off = 32; off > 0; off >>= 1) acc += __shfl_down(acc, off, 64);
    if ((tid & 63) == 0) wred[tid >> 6] = acc;
    __syncthreads();
    if (tid == 0) atomicAdd(out + b, wred[0] + wred[1] + wred[2] + wred[3]);
    if (blockIdx.x == 0 && blockIdx.z == 0 && tid < FF) {
        float v = bias[tid];
        for (int off = 32; off > 0; off >>= 1) v += __shfl_down(v, off, 64);
        if ((tid & 63) == 0) atomicAdd(out + b, v);
    }
}

// --------- Fallback (no workspace): one block per (f,b), LDS rows ----------
__global__ __launch_bounds__(256) void k_naive(
    const float* __restrict__ x, const float* __restrict__ cw,
    const float* __restrict__ sw, const float* __restrict__ weight,
    const float* __restrict__ bias, float* __restrict__ out)
{
    __shared__ float yl[TS];
    __shared__ float ql[TS];
    __shared__ float wred[4];
    const int f = blockIdx.x, b = blockIdx.y, tid = threadIdx.x;
    for (int t = tid; t < TS; t += 256) {
        float a = 0.f, s = 0.f;
        for (int c = 0; c < CINN; ++c) {
            float v = x[((size_t)b * CINN + c) * TS + t];
            a += sw[(size_t)f * CINN + c] * v;
            s += v * v;
        }
        yl[t] = a; ql[t] = s;
    }
    __syncthreads();
    float acc = 0.f;
    for (int t = tid; t < TOUT; t += 256) {
        float cv = 0.f, sl = 0.f;
        for (int k = 0; k < KS; ++k) { cv += cw[(size_t)f * KS + k] * yl[t + k]; sl += ql[t + k]; }
        acc += fabsf(cv) * rsqrtf(sl);
    }
    float ssw = 0.f, scw = 0.f;
    for (int c = 0; c < CINN; ++c) { float v = sw[(size_t)f * CINN + c]; ssw += v * v; }
    for (int k = 0; k < KS; ++k)   { float v = cw[(size_t)f * KS + k];  scw += v * v; }
    const float wnf = weight[f] * rsqrtf(ssw * scw) * 64.0f / (float)TOUT;
    for (int off = 32; off > 0; off >>= 1) acc += __shfl_down(acc, off, 64);
    if ((tid & 63) == 0) wred[tid >> 6] = acc;
    __syncthreads();
    if (tid == 0) {
        float tot = (wred[0] + wred[1] + wred[2] + wred[3]) * wnf;
        if (f == 0) {
            float bsum = 0.f;
            for (int ff = 0; ff < FF; ++ff) bsum += bias[ff];
            tot += bsum;
        }
        atomicAdd(out + b, tot);
    }
}

extern "C" void kernel_launch(void* const* d_in, const int* in_sizes, int n_in,
                              void* d_out, int out_size, void* d_ws, size_t ws_size,
                              hipStream_t stream) {
    const float* x  = (const float*)d_in[0];
    const float* cw = (const float*)d_in[1];   // [F,K]
    const float* sw = (const float*)d_in[2];   // [F,CIN]
    const float* w  = (const float*)d_in[3];   // [F]
    const float* bs = (const float*)d_in[4];   // [F]
    float* out = (float*)d_out;

    hipMemsetAsync(d_out, 0, (size_t)out_size * sizeof(float), stream);

    const size_t yBytes  = (size_t)BB * FF * TS * sizeof(__hip_bfloat16); // 67 MB
    const size_t sqBytes = (size_t)BB * TS * sizeof(float);               // 1 MB

    if (yBytes + sqBytes <= ws_size) {
        __hip_bfloat16* ybf = (__hip_bfloat16*)d_ws;
        float* sq = (float*)((char*)d_ws + yBytes);
        k_spatial_mfma <<<dim3(TS / TPB, BB), 256, 0, stream>>>(x, sw, ybf, sq);
        k_temporal_mfma<<<dim3(TS / TT, BB, FF / FGZ), 256, 0, stream>>>(ybf, sq, cw, sw, w, bs, out);
    } else {
        k_naive<<<dim3(FF, BB), 256, 0, stream>>>(x, cw, sw, w, bs, out);
    }
}